// Round 5
// baseline (550.649 us; speedup 1.0000x reference)
//
#include <hip/hip_runtime.h>

typedef __bf16 bf16;
typedef __attribute__((ext_vector_type(8))) __bf16 bf16x8;
typedef __attribute__((ext_vector_type(4))) __bf16 bf16x4;
typedef __attribute__((ext_vector_type(4))) float f32x4;

#define B_  32
#define S_  2048
#define DC  1024
#define DQ  1024
#define H_  512
#define M_  (B_*S_)

#define BM  64             // rows per block (one 64-row strip, 4 waves share it via L1)

// ---------- Prep: blocks 0..255 = Wc->bf16 transpose tiles; 256..511 = qb GEMV ----------
__global__ __launch_bounds__(256) void k_prep(const float* __restrict__ W1,
                                              const float* __restrict__ query,
                                              const float* __restrict__ b1,
                                              bf16* __restrict__ WcT2,
                                              float* __restrict__ qb) {
    const int bid = blockIdx.x, tid = threadIdx.x;
    if (bid < 256) {
        // W1[:1024] (k-major) -> WcT2 [kb(32)][col(512)][kk(32)] bf16
        __shared__ bf16 t[32 * 68];            // [kk][h-in-tile], pad 4
        const int kb = bid >> 3;               // 0..31
        const int cb = bid & 7;                // 0..7, 64-col tile
        #pragma unroll
        for (int i = 0; i < 2; ++i) {
            int idx = i * 256 + tid;           // 0..511
            int k  = idx >> 4;                 // 0..31
            int h4 = (idx & 15) * 4;           // 0..60
            const float4 v = *(const float4*)(W1 + ((size_t)(kb * 32 + k)) * H_ + cb * 64 + h4);
            bf16x4 pk = { (bf16)v.x, (bf16)v.y, (bf16)v.z, (bf16)v.w };
            *(bf16x4*)(&t[k * 68 + h4]) = pk;
        }
        __syncthreads();
        const int col = tid >> 2;              // 0..63
        const int kk0 = (tid & 3) * 8;         // 0,8,16,24
        bf16x8 o;
        #pragma unroll
        for (int j = 0; j < 8; ++j) o[j] = t[(kk0 + j) * 68 + col];
        *(bf16x8*)(WcT2 + (size_t)kb * 16384 + (size_t)(cb * 64 + col) * 32 + kk0) = o;
    } else {
        // qb[b][h] = query[b,:] . Wq[:,h] + b1[h]
        const int r = bid - 256;
        const int hblk = r & 7;                // 0..7
        const int b    = r >> 3;               // 0..31
        __shared__ float q[DQ];
        __shared__ float red[256];
        #pragma unroll
        for (int i = 0; i < 4; ++i)
            q[tid + i * 256] = query[(size_t)b * DQ + tid + i * 256];
        __syncthreads();
        const int h  = hblk * 64 + (tid & 63);
        const int kc = tid >> 6;               // 0..3
        const float* w = W1 + (size_t)DC * H_ + (size_t)(kc * 256) * H_ + h;
        const float* qv = q + kc * 256;
        float acc = 0.0f;
        #pragma unroll 8
        for (int k = 0; k < 256; ++k)
            acc = fmaf(qv[k], w[(size_t)k * H_], acc);
        red[tid] = acc;
        __syncthreads();
        if (tid < 64)
            qb[(size_t)b * H_ + hblk * 64 + tid] =
                red[tid] + red[tid + 64] + red[tid + 128] + red[tid + 192] + b1[hblk * 64 + tid];
    }
}

// ---------- Kernel G: score[row] = sum_h tanh(ctx@Wc + qb)[h]*w2[h] ----------
// NO LDS staging, NO K-loop barriers. 1024 blocks x 256 thr = 4 waves.
// Each wave: 64 rows x 128 cols (wn quarter of H), fragments loaded straight
// from global: B (1 MB, L1/L2-hot) as 16B/lane; A (ctx fp32) as 2xfloat4/lane
// with register prefetch of k+1 and in-register bf16 convert.
__global__ __launch_bounds__(256, 2) void k_gemm(const float* __restrict__ ctx,
                                                 const bf16*  __restrict__ WcT2,
                                                 const float* __restrict__ qb,
                                                 const float* __restrict__ W2,
                                                 float* __restrict__ score) {
    __shared__ float red[BM * 4];

    const int tid  = threadIdx.x;
    const int mblk = blockIdx.x;            // 0..1023
    const size_t row_base = (size_t)mblk * BM;
    const int b = mblk >> 5;                // 32 mblks per batch

    const int lane = tid & 63;
    const int wn   = tid >> 6;              // 0..3 -> cols [wn*128, +128)
    const int l16  = lane & 15;
    const int quad = lane >> 4;

    f32x4 acc[4][8] = {};

    // A row pointers: lane l16 -> row (mf*16 + l16), k-offset quad*8
    const float* arow[4];
    #pragma unroll
    for (int mf = 0; mf < 4; ++mf)
        arow[mf] = ctx + (row_base + mf * 16 + l16) * (size_t)DC + quad * 8;
    // B pointer: lane -> col (wn*128 + l16), kk quad*8; nf stride = 16 cols * 32 = 512
    const bf16* bptr = WcT2 + (size_t)(wn * 128 + l16) * 32 + quad * 8;

    float4 av0[2][4], av1[2][4];
    // prologue: load A for kb=0
    #pragma unroll
    for (int mf = 0; mf < 4; ++mf) {
        av0[0][mf] = *(const float4*)(arow[mf]);
        av1[0][mf] = *(const float4*)(arow[mf] + 4);
    }

    #pragma unroll 2
    for (int kb = 0; kb < 32; ++kb) {
        const int cur = kb & 1, nxt = cur ^ 1;
        // B fragments for this k-step (L1/L2-hot)
        bf16x8 bF[8];
        #pragma unroll
        for (int nf = 0; nf < 8; ++nf)
            bF[nf] = *(const bf16x8*)(bptr + (size_t)kb * 16384 + nf * 512);
        // prefetch A for k+1
        if (kb < 31) {
            #pragma unroll
            for (int mf = 0; mf < 4; ++mf) {
                av0[nxt][mf] = *(const float4*)(arow[mf] + (kb + 1) * 32);
                av1[nxt][mf] = *(const float4*)(arow[mf] + (kb + 1) * 32 + 4);
            }
        }
        // convert current A to bf16 fragments
        bf16x8 aF[4];
        #pragma unroll
        for (int mf = 0; mf < 4; ++mf) {
            const float4 v0 = av0[cur][mf], v1 = av1[cur][mf];
            aF[mf] = bf16x8{ (bf16)v0.x, (bf16)v0.y, (bf16)v0.z, (bf16)v0.w,
                             (bf16)v1.x, (bf16)v1.y, (bf16)v1.z, (bf16)v1.w };
        }
        #pragma unroll
        for (int mf = 0; mf < 4; ++mf)
            #pragma unroll
            for (int nf = 0; nf < 8; ++nf)
                acc[mf][nf] = __builtin_amdgcn_mfma_f32_16x16x32_bf16(aF[mf], bF[nf], acc[mf][nf], 0, 0, 0);
    }

    // epilogue: s(row) = sum over this wave's 128 cols of tanh(acc+qb)*w2
    float qv[8], wv[8];
    #pragma unroll
    for (int nf = 0; nf < 8; ++nf) {
        int c = wn * 128 + nf * 16 + l16;
        qv[nf] = qb[(size_t)b * H_ + c];
        wv[nf] = W2[c];
    }
    #pragma unroll
    for (int mf = 0; mf < 4; ++mf) {
        #pragma unroll
        for (int r = 0; r < 4; ++r) {
            float s = 0.0f;
            #pragma unroll
            for (int nf = 0; nf < 8; ++nf) {
                float x = acc[mf][nf][r] + qv[nf];
                float t = 1.0f - 2.0f / (1.0f + __expf(2.0f * x)); // tanh, saturates
                s = fmaf(t, wv[nf], s);
            }
            s += __shfl_xor(s, 1);
            s += __shfl_xor(s, 2);
            s += __shfl_xor(s, 4);
            s += __shfl_xor(s, 8);
            if (l16 == 0)
                red[(mf * 16 + quad * 4 + r) * 4 + wn] = s;
        }
    }
    __syncthreads();
    if (tid < BM)
        score[row_base + tid] = red[tid * 4] + red[tid * 4 + 1] + red[tid * 4 + 2] + red[tid * 4 + 3];
}

// ---------- Kernel S: + b2, mask, stable softmax per batch row -> p_out ----------
__global__ __launch_bounds__(256) void k_softmax(const float* __restrict__ score,
                                                 const float* __restrict__ b2,
                                                 const int*   __restrict__ mask,
                                                 float* __restrict__ p_out) {
    int b = blockIdx.x, tid = threadIdx.x;
    __shared__ float red[256];
    float loc[8];
    float b2v = b2[0];
    float mx = -1e30f;
    #pragma unroll
    for (int i = 0; i < 8; ++i) {
        size_t r = (size_t)b * S_ + i * 256 + tid;
        float v = score[r] + b2v;
        if (mask[r] == 0) v = -10000.0f;
        loc[i] = v;
        mx = fmaxf(mx, v);
    }
    red[tid] = mx; __syncthreads();
    for (int o = 128; o > 0; o >>= 1) {
        if (tid < o) red[tid] = fmaxf(red[tid], red[tid + o]);
        __syncthreads();
    }
    mx = red[0]; __syncthreads();
    float se = 0.0f;
    #pragma unroll
    for (int i = 0; i < 8; ++i) {
        float e = __expf(loc[i] - mx);
        loc[i] = e;
        se += e;
    }
    red[tid] = se; __syncthreads();
    for (int o = 128; o > 0; o >>= 1) {
        if (tid < o) red[tid] += red[tid + o];
        __syncthreads();
    }
    float inv = 1.0f / red[0];
    #pragma unroll
    for (int i = 0; i < 8; ++i)
        p_out[(size_t)b * S_ + i * 256 + tid] = loc[i] * inv;
}

// ---------- Kernel E: partial expected_ctx over 64-row s-chunks ----------
// grid (32 sblk, 32 b) = 1024 blocks, 256 thr, float4 streaming.
__global__ __launch_bounds__(256) void k_expected(const float* __restrict__ ctx,
                                                  const float* __restrict__ p,
                                                  float* __restrict__ partial) {
    const int sb = blockIdx.x, b = blockIdx.y, tid = threadIdx.x;
    __shared__ float ps[64];
    if (tid < 64) ps[tid] = p[(size_t)b * S_ + sb * 64 + tid];
    __syncthreads();
    const float* base = ctx + ((size_t)b * S_ + sb * 64) * DC + tid * 4;
    float ax = 0.f, ay = 0.f, az = 0.f, aw = 0.f;
    #pragma unroll 8
    for (int s = 0; s < 64; ++s) {
        const float4 v = *(const float4*)(base + (size_t)s * DC);
        float w = ps[s];
        ax = fmaf(w, v.x, ax);
        ay = fmaf(w, v.y, ay);
        az = fmaf(w, v.z, az);
        aw = fmaf(w, v.w, aw);
    }
    float4 o = { ax, ay, az, aw };
    *(float4*)(partial + ((size_t)(b * 32 + sb)) * DC + tid * 4) = o;
}

// ---------- Kernel R: reduce 32 chunks -> expected_ctx ----------
// grid (4, 32), 256 thr, one col per thread (coalesced).
__global__ __launch_bounds__(256) void k_reduce(const float* __restrict__ partial,
                                                float* __restrict__ out) {
    const int cq = blockIdx.x, b = blockIdx.y, tid = threadIdx.x;
    const int c = cq * 256 + tid;
    float acc = 0.f;
    #pragma unroll
    for (int sb = 0; sb < 32; ++sb)
        acc += partial[((size_t)(b * 32 + sb)) * DC + c];
    out[(size_t)b * DC + c] = acc;
}

extern "C" void kernel_launch(void* const* d_in, const int* in_sizes, int n_in,
                              void* d_out, int out_size, void* d_ws, size_t ws_size,
                              hipStream_t stream) {
    (void)in_sizes; (void)n_in; (void)out_size; (void)ws_size;
    const float* ctx   = (const float*)d_in[0];
    const float* query = (const float*)d_in[1];
    const float* W1    = (const float*)d_in[2];
    const float* b1    = (const float*)d_in[3];
    const float* W2    = (const float*)d_in[4];
    const float* b2    = (const float*)d_in[5];
    const int*   mask  = (const int*)d_in[6];

    float* out      = (float*)d_out;
    float* expected = out;                 // 32*1024
    float* p_out    = out + 32768;         // 32*2048

    char* w = (char*)d_ws;
    bf16*  WcT2      = (bf16*)w;                                    // 1 MB  [kb][col][kk]
    float* qb        = (float*)(w + (1 << 20));                     // 64 KB
    float* score     = (float*)(w + (1 << 20) + (64 << 10));        // 256 KB
    float* partial_e = (float*)(w + (1 << 20) + (320 << 10));       // 32*32*1024 fp32 = 4 MB

    k_prep    <<<512, 256, 0, stream>>>(W1, query, b1, WcT2, qb);
    k_gemm    <<<M_ / BM, 256, 0, stream>>>(ctx, WcT2, qb, W2, score);
    k_softmax <<<B_, 256, 0, stream>>>(score, b2, mask, p_out);
    k_expected<<<dim3(32, B_), 256, 0, stream>>>(ctx, p_out, partial_e);
    k_reduce  <<<dim3(4, B_), 256, 0, stream>>>(partial_e, expected);
}

// Round 6
// 538.315 us; speedup vs baseline: 1.0229x; 1.0229x over previous
//
#include <hip/hip_runtime.h>

typedef __bf16 bf16;
typedef __attribute__((ext_vector_type(8))) __bf16 bf16x8;
typedef __attribute__((ext_vector_type(4))) __bf16 bf16x4;
typedef __attribute__((ext_vector_type(4))) float f32x4;

#define B_  32
#define S_  2048
#define DC  1024
#define DQ  1024
#define H_  512
#define M_  (B_*S_)

#define BM  64             // rows per gemm block
#define BK  32

// LDS slot swizzle: slot s (16B chunks) -> bf16 index; +2 bf16 per 8 slots
// breaks the 8-way bank alias of a pure s*16 layout on both write and read.
__device__ __forceinline__ int aoff(int s) { return s * 8 + (s >> 3) * 2; }

// ---------- Prep: blocks 0..255 = Wc->bf16 transpose tiles; 256..511 = qb GEMV ----------
__global__ __launch_bounds__(256) void k_prep(const float* __restrict__ W1,
                                              const float* __restrict__ query,
                                              const float* __restrict__ b1,
                                              bf16* __restrict__ WcT2,
                                              float* __restrict__ qb) {
    const int bid = blockIdx.x, tid = threadIdx.x;
    if (bid < 256) {
        // W1[:1024] (k-major) -> WcT2 [kb(32)][col(512)][kk(32)] bf16
        __shared__ bf16 t[32 * 68];            // [kk][h-in-tile], pad 4
        const int kb = bid >> 3;               // 0..31
        const int cb = bid & 7;                // 0..7, 64-col tile
        #pragma unroll
        for (int i = 0; i < 2; ++i) {
            int idx = i * 256 + tid;           // 0..511
            int k  = idx >> 4;                 // 0..31
            int h4 = (idx & 15) * 4;           // 0..60
            const float4 v = *(const float4*)(W1 + ((size_t)(kb * 32 + k)) * H_ + cb * 64 + h4);
            bf16x4 pk = { (bf16)v.x, (bf16)v.y, (bf16)v.z, (bf16)v.w };
            *(bf16x4*)(&t[k * 68 + h4]) = pk;
        }
        __syncthreads();
        const int col = tid >> 2;              // 0..63
        const int kk0 = (tid & 3) * 8;         // 0,8,16,24
        bf16x8 o;
        #pragma unroll
        for (int j = 0; j < 8; ++j) o[j] = t[(kk0 + j) * 68 + col];
        *(bf16x8*)(WcT2 + (size_t)kb * 16384 + (size_t)(cb * 64 + col) * 32 + kk0) = o;
    } else {
        // qb[b][h] = query[b,:] . Wq[:,h] + b1[h]
        const int r = bid - 256;
        const int hblk = r & 7;                // 0..7
        const int b    = r >> 3;               // 0..31
        __shared__ float q[DQ];
        __shared__ float red[256];
        #pragma unroll
        for (int i = 0; i < 4; ++i)
            q[tid + i * 256] = query[(size_t)b * DQ + tid + i * 256];
        __syncthreads();
        const int h  = hblk * 64 + (tid & 63);
        const int kc = tid >> 6;               // 0..3
        const float* w = W1 + (size_t)DC * H_ + (size_t)(kc * 256) * H_ + h;
        const float* qv = q + kc * 256;
        float acc = 0.0f;
        #pragma unroll 8
        for (int k = 0; k < 256; ++k)
            acc = fmaf(qv[k], w[(size_t)k * H_], acc);
        red[tid] = acc;
        __syncthreads();
        if (tid < 64)
            qb[(size_t)b * H_ + hblk * 64 + tid] =
                red[tid] + red[tid + 64] + red[tid + 128] + red[tid + 192] + b1[hblk * 64 + tid];
    }
}

// ---------- Kernel G ----------
// 1024 blocks x 256 thr (4 waves, wave = 64 rows x 128 cols).
// A: fp32 ctx -> registers -> bf16 -> tiny LDS (8.7 KB dbuf) in fragment order
//    (all 4 waves read the SAME A fragments -> broadcast), optional ctxb store.
// B: registers straight from WcT2 (L2-hot), issued FIRST each k-step so the
//    MFMA s_waitcnt is vmcnt(B-only); A loads queue behind and are consumed
//    late (cvt phase), so their latency never gates the MFMAs.
template<bool STORE>
__global__ __launch_bounds__(256, 2) void k_gemm(const float* __restrict__ ctx,
                                                 const bf16*  __restrict__ WcT2,
                                                 const float* __restrict__ qb,
                                                 const float* __restrict__ W2,
                                                 float* __restrict__ score,
                                                 bf16* __restrict__ ctxb) {
    __shared__ bf16 As[2][2176];           // swizzled: 256 slots x 16 B + pad
    __shared__ float red[BM * 4];

    const int tid  = threadIdx.x;
    const int mblk = blockIdx.x;           // 0..1023
    const size_t row_base = (size_t)mblk * BM;
    const int b = mblk >> 5;

    const int lane = tid & 63;
    const int wn   = tid >> 6;             // 0..3 -> cols [wn*128, +128)
    const int l16  = lane & 15;
    const int quad = lane >> 4;

    f32x4 acc[4][8] = {};

    // staging map: thread t <-> chunk t: row = (t>>6)*16 + (t&15), q = (t>>4)&3
    const int srow = (tid >> 6) * 16 + (tid & 15);
    const int sq   = (tid >> 4) & 3;
    const float* asrc = ctx + (row_base + srow) * (size_t)DC + sq * 8;
    bf16* adst = STORE ? (ctxb + (row_base + srow) * (size_t)DC + sq * 8) : (bf16*)nullptr;
    const int awr = aoff(tid);
    // fragment read offsets: lane reads slot mf*64 + lane
    int ard[4];
    #pragma unroll
    for (int mf = 0; mf < 4; ++mf) ard[mf] = aoff(mf * 64 + lane);
    // B pointer
    const bf16* bptr = WcT2 + (size_t)(wn * 128 + l16) * 32 + quad * 8;

    // ---- prologue: stage k-step 0 ----
    {
        const float4 v0 = *(const float4*)(asrc);
        const float4 v1 = *(const float4*)(asrc + 4);
        bf16x8 a8 = { (bf16)v0.x, (bf16)v0.y, (bf16)v0.z, (bf16)v0.w,
                      (bf16)v1.x, (bf16)v1.y, (bf16)v1.z, (bf16)v1.w };
        *(bf16x8*)(&As[0][awr]) = a8;
        if (STORE) *(bf16x8*)adst = a8;
    }
    __syncthreads();

    for (int kb = 0; kb < 32; ++kb) {
        const int cur = kb & 1, nxt = cur ^ 1;
        // 1) B fragments for THIS step — first in the vmcnt queue
        bf16x8 bF[8];
        #pragma unroll
        for (int nf = 0; nf < 8; ++nf)
            bF[nf] = *(const bf16x8*)(bptr + (size_t)kb * 16384 + nf * 512);
        // 2) A fp32 prefetch for step kb+1 (queued behind B)
        float4 av0, av1;
        if (kb < 31) {
            av0 = *(const float4*)(asrc + (kb + 1) * BK);
            av1 = *(const float4*)(asrc + (kb + 1) * BK + 4);
        }
        // 3) A fragments from LDS (staged last step)
        bf16x8 aF[4];
        #pragma unroll
        for (int mf = 0; mf < 4; ++mf)
            aF[mf] = *(const bf16x8*)(&As[cur][ard[mf]]);
        // 4) MFMAs — wait only on B (and lgkm for aF)
        #pragma unroll
        for (int mf = 0; mf < 4; ++mf)
            #pragma unroll
            for (int nf = 0; nf < 8; ++nf)
                acc[mf][nf] = __builtin_amdgcn_mfma_f32_16x16x32_bf16(aF[mf], bF[nf], acc[mf][nf], 0, 0, 0);
        // 5) convert + stage A(kb+1); optional ctxb write-out
        if (kb < 31) {
            bf16x8 a8 = { (bf16)av0.x, (bf16)av0.y, (bf16)av0.z, (bf16)av0.w,
                          (bf16)av1.x, (bf16)av1.y, (bf16)av1.z, (bf16)av1.w };
            *(bf16x8*)(&As[nxt][awr]) = a8;
            if (STORE) *(bf16x8*)(adst + (kb + 1) * BK) = a8;
        }
        __syncthreads();
    }

    // ---- epilogue ----
    float qv[8], wv[8];
    #pragma unroll
    for (int nf = 0; nf < 8; ++nf) {
        int c = wn * 128 + nf * 16 + l16;
        qv[nf] = qb[(size_t)b * H_ + c];
        wv[nf] = W2[c];
    }
    #pragma unroll
    for (int mf = 0; mf < 4; ++mf) {
        #pragma unroll
        for (int r = 0; r < 4; ++r) {
            float s = 0.0f;
            #pragma unroll
            for (int nf = 0; nf < 8; ++nf) {
                float x = acc[mf][nf][r] + qv[nf];
                float t = 1.0f - 2.0f / (1.0f + __expf(2.0f * x)); // tanh, saturates
                s = fmaf(t, wv[nf], s);
            }
            s += __shfl_xor(s, 1);
            s += __shfl_xor(s, 2);
            s += __shfl_xor(s, 4);
            s += __shfl_xor(s, 8);
            if (l16 == 0)
                red[(mf * 16 + quad * 4 + r) * 4 + wn] = s;
        }
    }
    __syncthreads();
    if (tid < BM)
        score[row_base + tid] = red[tid * 4] + red[tid * 4 + 1] + red[tid * 4 + 2] + red[tid * 4 + 3];
}

// ---------- Kernel S: + b2, mask, stable softmax per batch row -> p_out ----------
__global__ __launch_bounds__(256) void k_softmax(const float* __restrict__ score,
                                                 const float* __restrict__ b2,
                                                 const int*   __restrict__ mask,
                                                 float* __restrict__ p_out) {
    int b = blockIdx.x, tid = threadIdx.x;
    __shared__ float red[256];
    float loc[8];
    float b2v = b2[0];
    float mx = -1e30f;
    #pragma unroll
    for (int i = 0; i < 8; ++i) {
        size_t r = (size_t)b * S_ + i * 256 + tid;
        float v = score[r] + b2v;
        if (mask[r] == 0) v = -10000.0f;
        loc[i] = v;
        mx = fmaxf(mx, v);
    }
    red[tid] = mx; __syncthreads();
    for (int o = 128; o > 0; o >>= 1) {
        if (tid < o) red[tid] = fmaxf(red[tid], red[tid + o]);
        __syncthreads();
    }
    mx = red[0]; __syncthreads();
    float se = 0.0f;
    #pragma unroll
    for (int i = 0; i < 8; ++i) {
        float e = __expf(loc[i] - mx);
        loc[i] = e;
        se += e;
    }
    red[tid] = se; __syncthreads();
    for (int o = 128; o > 0; o >>= 1) {
        if (tid < o) red[tid] += red[tid + o];
        __syncthreads();
    }
    float inv = 1.0f / red[0];
    #pragma unroll
    for (int i = 0; i < 8; ++i)
        p_out[(size_t)b * S_ + i * 256 + tid] = loc[i] * inv;
}

// ---------- Kernel E: partial expected_ctx over 64-row s-chunks ----------
// grid (32 sblk, 32 b) = 1024 blocks, 256 thr. BF: reads bf16 ctxb (8B/lane).
template<bool BF>
__global__ __launch_bounds__(256) void k_expected(const float* __restrict__ ctxf,
                                                  const bf16*  __restrict__ ctxb,
                                                  const float* __restrict__ p,
                                                  float* __restrict__ partial) {
    const int sb = blockIdx.x, b = blockIdx.y, tid = threadIdx.x;
    __shared__ float ps[64];
    if (tid < 64) ps[tid] = p[(size_t)b * S_ + sb * 64 + tid];
    __syncthreads();
    float ax = 0.f, ay = 0.f, az = 0.f, aw = 0.f;
    if (BF) {
        const bf16* base = ctxb + ((size_t)b * S_ + sb * 64) * DC + tid * 4;
        #pragma unroll 8
        for (int s = 0; s < 64; ++s) {
            bf16x4 v = *(const bf16x4*)(base + (size_t)s * DC);
            float w = ps[s];
            ax = fmaf(w, (float)v[0], ax);
            ay = fmaf(w, (float)v[1], ay);
            az = fmaf(w, (float)v[2], az);
            aw = fmaf(w, (float)v[3], aw);
        }
    } else {
        const float* base = ctxf + ((size_t)b * S_ + sb * 64) * DC + tid * 4;
        #pragma unroll 8
        for (int s = 0; s < 64; ++s) {
            const float4 v = *(const float4*)(base + (size_t)s * DC);
            float w = ps[s];
            ax = fmaf(w, v.x, ax);
            ay = fmaf(w, v.y, ay);
            az = fmaf(w, v.z, az);
            aw = fmaf(w, v.w, aw);
        }
    }
    float4 o = { ax, ay, az, aw };
    *(float4*)(partial + ((size_t)(b * 32 + sb)) * DC + tid * 4) = o;
}

// ---------- Kernel R: reduce 32 chunks -> expected_ctx ----------
__global__ __launch_bounds__(256) void k_reduce(const float* __restrict__ partial,
                                                float* __restrict__ out) {
    const int cq = blockIdx.x, b = blockIdx.y, tid = threadIdx.x;
    const int c = cq * 256 + tid;
    float acc = 0.f;
    #pragma unroll
    for (int sb = 0; sb < 32; ++sb)
        acc += partial[((size_t)(b * 32 + sb)) * DC + c];
    out[(size_t)b * DC + c] = acc;
}

extern "C" void kernel_launch(void* const* d_in, const int* in_sizes, int n_in,
                              void* d_out, int out_size, void* d_ws, size_t ws_size,
                              hipStream_t stream) {
    (void)in_sizes; (void)n_in; (void)out_size;
    const float* ctx   = (const float*)d_in[0];
    const float* query = (const float*)d_in[1];
    const float* W1    = (const float*)d_in[2];
    const float* b1    = (const float*)d_in[3];
    const float* W2    = (const float*)d_in[4];
    const float* b2    = (const float*)d_in[5];
    const int*   mask  = (const int*)d_in[6];

    float* out      = (float*)d_out;
    float* expected = out;                 // 32*1024
    float* p_out    = out + 32768;         // 32*2048

    const size_t CTXB = (size_t)M_ * DC * sizeof(bf16);   // 128 MB
    const size_t tail = (1 << 20) + (64 << 10) + (256 << 10) + (4 << 20) + 256;
    char* w = (char*)d_ws;

    if (ws_size >= CTXB + tail) {
        bf16*  ctxb   = (bf16*)w;
        bf16*  WcT2   = (bf16*)(w + CTXB);
        float* qb     = (float*)(w + CTXB + (1 << 20));
        float* score  = (float*)(w + CTXB + (1 << 20) + (64 << 10));
        float* partial= (float*)(w + CTXB + (1 << 20) + (320 << 10));
        k_prep          <<<512, 256, 0, stream>>>(W1, query, b1, WcT2, qb);
        k_gemm<true>    <<<M_ / BM, 256, 0, stream>>>(ctx, WcT2, qb, W2, score, ctxb);
        k_softmax       <<<B_, 256, 0, stream>>>(score, b2, mask, p_out);
        k_expected<true><<<dim3(32, B_), 256, 0, stream>>>(ctx, ctxb, p_out, partial);
        k_reduce        <<<dim3(4, B_), 256, 0, stream>>>(partial, expected);
    } else {
        bf16*  WcT2   = (bf16*)w;
        float* qb     = (float*)(w + (1 << 20));
        float* score  = (float*)(w + (1 << 20) + (64 << 10));
        float* partial= (float*)(w + (1 << 20) + (320 << 10));
        k_prep           <<<512, 256, 0, stream>>>(W1, query, b1, WcT2, qb);
        k_gemm<false>    <<<M_ / BM, 256, 0, stream>>>(ctx, WcT2, qb, W2, score, nullptr);
        k_softmax        <<<B_, 256, 0, stream>>>(score, b2, mask, p_out);
        k_expected<false><<<dim3(32, B_), 256, 0, stream>>>(ctx, nullptr, p_out, partial);
        k_reduce         <<<dim3(4, B_), 256, 0, stream>>>(partial, expected);
    }
}